// Round 12
// baseline (19.844 us; speedup 1.0000x reference)
//
#include <hip/hip_runtime.h>
#include <hip/hip_bf16.h>

// FrameReducer: N=16, T=2048, C=512, V=500 — two dispatches.
//
// Kernel 1 (mask_emit): grid (B=T/128, N) x 128 thr = 256 blocks (full chip),
//   ONE strided ctc load per thread. Stable segment-local compaction:
//   seg[n][b*128 + local] = t, cnt[n][b] = count.
// Kernel 2 (gather): grid (ceil(Tp*128/256), N), 256 thr, one 16B vec/thread.
//   NO LDS, NO barrier, NO shfl scan (R11's per-block preamble cost ~1us
//   across 9.3K blocks): each thread walks cnt[n][0..B) — block-uniform
//   scalar L1-hit loads — accumulating prefix to find (segment, offset) and
//   lens in registers (~60 predicated VALU ops, hidden under memory stream).
//   Regular x loads (L3-resident), NT stores (R9 win: write-once stream).
//   Zero tail rows written every call (harness poisons d_out once only).
//   Block (0,n) thread 0 writes the float lens tail of d_out.

typedef float f32x4 __attribute__((ext_vector_type(4)));

__global__ __launch_bounds__(128) void mask_emit_kernel(
        const float* __restrict__ ctc,
        const void* __restrict__ x_lens_raw,
        const int* __restrict__ blank_id_p,
        int N, int T, int V,
        int* __restrict__ seg,
        int* __restrict__ cnt) {
    const int n    = blockIdx.y;
    const int b    = blockIdx.x;          // segment id, 128 t's each
    const int tid  = threadIdx.x;         // 128 = 2 waves
    const int lane = tid & 63;
    const int w    = tid >> 6;
    const int B    = gridDim.x;
    const int t    = b * 128 + tid;

    // x_lens dtype detection: values in [1,T], never 0 -> int64 layout iff
    // int32 view at odd index is 0.
    const int* li = (const int*)x_lens_raw;
    long long L = (N > 1 && li[1] == 0) ? ((const long long*)x_lens_raw)[n]
                                        : (long long)li[n];

    bool keep = false;
    if (t < T) {
        float v = ctc[((long long)n * T + t) * V + *blank_id_p];
        keep = (v < -0.10536052f) && ((long long)t < L);   // float32(log(0.9))
    }
    unsigned long long bal = __ballot(keep);

    __shared__ int w0cnt;
    if (w == 0 && lane == 0) w0cnt = __popcll(bal);
    __syncthreads();

    const int base = (w == 0) ? 0 : w0cnt;
    if (keep) {
        int rank = __popcll(bal & ((1ull << lane) - 1ull));
        seg[n * T + b * 128 + base + rank] = t;
    }
    if (w == 1 && lane == 0) cnt[n * B + b] = w0cnt + __popcll(bal);
}

__global__ __launch_bounds__(256) void gather_kernel(
        const f32x4* __restrict__ x,
        const int* __restrict__ seg,
        const int* __restrict__ cnt,
        f32x4* __restrict__ out,
        float* __restrict__ lens_out,
        int Tp, int T, int B, int f4_per_seq) {
    const int n   = blockIdx.y;
    const int gid = blockIdx.x * 256 + threadIdx.x;   // f4 index within sequence
    const int p   = gid >> 7;                         // row (128 f4/row, C=512)
    const int c4  = gid & 127;

    // Register walk of segment counts: find my segment i, its prefix acc,
    // and total lens — no LDS, no sync. cnt address is block-uniform -> the
    // loads are scalar and L1-resident (64B for B=16).
    const int* c = cnt + n * B;
    int acc = 0;      // prefix before segment i
    int i   = -1;     // my segment
    int lens = 0;
    for (int k = 0; k < B; ++k) {
        int ck = c[k];
        if (i < 0 && lens + ck > p) { i = k; acc = lens; }
        lens += ck;
    }

    if (blockIdx.x == 0 && threadIdx.x == 0) lens_out[n] = (float)lens;
    if (gid >= f4_per_seq) return;

    f32x4 v = (f32x4)0.f;
    if (p < lens) {
        int tsrc = seg[n * T + (i << 7) + (p - acc)];   // wave-uniform broadcast
        v = x[((long long)(n * T + tsrc) << 7) + c4];   // regular load (L3)
    }
    __builtin_nontemporal_store(v, out + ((long long)n * Tp << 7) + gid);
}

extern "C" void kernel_launch(void* const* d_in, const int* in_sizes, int n_in,
                              void* d_out, int out_size, void* d_ws, size_t ws_size,
                              hipStream_t stream) {
    const float* x        = (const float*)d_in[0];
    const void*  x_lens   = d_in[1];
    const float* ctc      = (const float*)d_in[2];
    const int*   blank_id = (const int*)d_in[3];

    const int N = in_sizes[1];               // 16
    const int C = 512;
    const int V = 500;
    const int T = in_sizes[0] / (N * C);     // 2048
    const int Tp = (out_size - N) / (N * C); // T'
    const int B = (T + 127) / 128;           // 16 segments per sequence

    int* seg = (int*)d_ws;                   // [N][T] (segment-local compaction)
    int* cnt = seg + (long long)N * T;       // [N][B]

    float* out      = (float*)d_out;                   // [N][Tp][C]
    float* lens_out = out + (long long)N * Tp * C;     // [N] float

    dim3 mgrid(B, N);
    mask_emit_kernel<<<mgrid, 128, 0, stream>>>(ctc, x_lens, blank_id,
                                                N, T, V, seg, cnt);

    const int f4_per_seq = Tp * (C / 4);     // Tp*128
    dim3 ggrid((f4_per_seq + 255) / 256, N);
    gather_kernel<<<ggrid, 256, 0, stream>>>((const f32x4*)x, seg, cnt,
                                             (f32x4*)out, lens_out,
                                             Tp, T, B, f4_per_seq);
}

// Round 13
// 16.770 us; speedup vs baseline: 1.1833x; 1.1833x over previous
//
#include <hip/hip_runtime.h>
#include <hip/hip_bf16.h>

// FrameReducer: N=16, T=2048, C=512, V=500 — FINAL (R9 structure, confirmed best).
//
// Round ledger: R9=16.89us beat 8 structural variants (17.8-22.4). Confirmed
// mechanisms: (1) non-temporal output stores (-2.0us: 30MB write-once stream
// skips cache allocation); (2) gather body kept to exactly {scalar lens,
// scalar idx, f4 load, NT store} — every added per-block/per-thread preamble
// (shfl scan, register count-walk, mask recompute) cost ≥1us. Cooperative
// grid.sync costs ~50us/barrier on MI355X (R4) — never again for us-scale.
//
// Kernel 1 (compact): N blocks x 1024 thr. keep[t] = (ctc[n,t,blank] <
//   log(0.9)) && (t < x_lens[n]); wave ballots -> chunk counts in LDS ->
//   thread-0 scan (32 entries, once per block, negligible) -> stable idx emit.
//   Writes lens[n] + float lens tail of d_out. ~2us: latency-bound strided
//   reads on 16 CUs; full-chip alternatives saved <1us and cost more in gather.
// Kernel 2 (gather): grid (ceil(Tp*128/256), N), one 16B vec/thread.
//   blockIdx.y = n (no int div). Wave-uniform p -> lens/idx scalar L1 hits.
//   Regular x loads (L3-resident), NT stores. Tail rows write zeros every
//   call (harness poisons d_out once, never re-poisons).

typedef float f32x4 __attribute__((ext_vector_type(4)));

__global__ void compact_kernel(const float* __restrict__ ctc,
                               const void* __restrict__ x_lens_raw,
                               const int* __restrict__ blank_id_p,
                               int T, int V, int N,
                               int* __restrict__ idx,
                               int* __restrict__ lens,
                               float* __restrict__ lens_out) {
    const int n    = blockIdx.x;
    const int tid  = threadIdx.x;          // 1024 threads = 16 waves
    const int lane = tid & 63;
    const int wid  = tid >> 6;
    const int ITERS = (T + 1023) >> 10;    // 2 for T=2048
    const int NCHUNK = ITERS * 16;         // 32

    __shared__ int wcnt[64];
    __shared__ int pfx[65];

    // x_lens dtype detection: values in [1,T], never 0 -> int64 layout iff
    // int32 view at odd index is 0.
    const int* li = (const int*)x_lens_raw;
    long long L;
    if (N > 1 && li[1] == 0) {
        L = ((const long long*)x_lens_raw)[n];
    } else {
        L = (long long)li[n];
    }

    const int blank = *blank_id_p;
    const float thr = -0.10536052f;        // float32(log(0.9))

    unsigned long long bal[4];
    #pragma unroll
    for (int j = 0; j < 4; ++j) bal[j] = 0ull;

    for (int j = 0; j < ITERS; ++j) {
        int t = (j << 10) + tid;
        bool keep = false;
        if (t < T) {
            float v = ctc[((long long)n * T + t) * V + blank];
            keep = (v < thr) && ((long long)t < L);
        }
        bal[j] = __ballot(keep);
        if (lane == 0) wcnt[j * 16 + wid] = __popcll(bal[j]);
    }
    __syncthreads();

    if (tid == 0) {
        int acc = 0;
        for (int c = 0; c < NCHUNK; ++c) { pfx[c] = acc; acc += wcnt[c]; }
        pfx[NCHUNK] = acc;
        lens[n] = acc;
        __builtin_nontemporal_store((float)acc, lens_out + n);
    }
    __syncthreads();

    int* my_idx = idx + (long long)n * T;
    for (int j = 0; j < ITERS; ++j) {
        int t = (j << 10) + tid;
        unsigned long long b = bal[j];
        if (b & (1ull << lane)) {
            int rank = __popcll(b & ((1ull << lane) - 1ull));
            my_idx[pfx[j * 16 + wid] + rank] = t;
        }
    }
}

__global__ __launch_bounds__(256) void gather_kernel(
        const f32x4* __restrict__ x,
        const int* __restrict__ idx,
        const int* __restrict__ lens,
        f32x4* __restrict__ out,
        int Tp, int T, int f4_per_seq) {
    const int n   = blockIdx.y;
    const int gid = blockIdx.x * 256 + threadIdx.x;   // f4 index within sequence
    if (gid >= f4_per_seq) return;
    const int p  = gid >> 7;                          // 128 f4 per row (C=512)
    const int c4 = gid & 127;

    f32x4 v = (f32x4)0.f;
    if (p < lens[n]) {                                // wave-uniform scalar
        int tsrc = idx[n * T + p];                    // wave-uniform scalar
        v = x[((long long)(n * T + tsrc) << 7) + c4];
    }
    __builtin_nontemporal_store(v, out + ((long long)n * Tp << 7) + gid);
}

extern "C" void kernel_launch(void* const* d_in, const int* in_sizes, int n_in,
                              void* d_out, int out_size, void* d_ws, size_t ws_size,
                              hipStream_t stream) {
    const float* x        = (const float*)d_in[0];
    const void*  x_lens   = d_in[1];
    const float* ctc      = (const float*)d_in[2];
    const int*   blank_id = (const int*)d_in[3];

    const int N = in_sizes[1];               // 16
    const int C = 512;
    const int V = 500;
    const int T = in_sizes[0] / (N * C);     // 2048
    const int Tp = (out_size - N) / (N * C); // T'

    int* idx  = (int*)d_ws;                  // [N][T]
    int* lens = idx + (long long)N * T;      // [N]

    float* out      = (float*)d_out;                   // [N][Tp][C]
    float* lens_out = out + (long long)N * Tp * C;     // [N] float

    compact_kernel<<<N, 1024, 0, stream>>>(ctc, x_lens, blank_id, T, V, N,
                                           idx, lens, lens_out);

    const int f4_per_seq = Tp * (C / 4);     // Tp*128
    dim3 ggrid((f4_per_seq + 255) / 256, N);
    gather_kernel<<<ggrid, 256, 0, stream>>>((const f32x4*)x, idx, lens,
                                             (f32x4*)out, Tp, T, f4_per_seq);
}